// Round 3
// baseline (648.503 us; speedup 1.0000x reference)
//
#include <hip/hip_runtime.h>
#include <math.h>

#define HW 4096
#define PLSTRIDE ((size_t)HW * 8)   // elements per 8-channel plane of A

typedef unsigned short ushort_t;
typedef short v8s __attribute__((ext_vector_type(8)));
typedef float v4f __attribute__((ext_vector_type(4)));

__device__ __forceinline__ float bf2f(ushort_t u) {
    union { unsigned int i; float f; } v; v.i = ((unsigned int)u) << 16; return v.f;
}
__device__ __forceinline__ ushort_t f2bf(float f) {
    unsigned int x = __float_as_uint(f);
    x += 0x7fffu + ((x >> 16) & 1u);   // RNE
    return (ushort_t)(x >> 16);
}

// async global->LDS, 16B per lane; LDS dest = wave-uniform base + lane*16
__device__ __forceinline__ void gld16(const ushort_t* g, ushort_t* l) {
    __builtin_amdgcn_global_load_lds(
        (__attribute__((address_space(1))) void*)g,
        (__attribute__((address_space(3))) void*)l, 16, 0, 0);
}

// ---------------- per-channel constants -------------------------------------
// cbuf layout (floats): [0]=sE [256]=cE [512]=s1 [768]=c1 [1024]=s2 [1280]=c2
__global__ __launch_bounds__(256) void k_consts(
    const float* eg, const float* ebt, const float* em, const float* ev,
    const float* fb,
    const float* g1, const float* b1, const float* m1, const float* v1,
    const float* balb,
    const float* g2, const float* b2, const float* m2, const float* v2,
    float* cbuf)
{
    int c = threadIdx.x;
    float iE = eg[c] * rsqrtf(ev[c] + 1e-5f);
    cbuf[c]       = iE;
    cbuf[256 + c] = ebt[c] - em[c] * iE;
    float i1 = g1[c] * rsqrtf(v1[c] + 1e-5f);
    cbuf[512 + c] = i1;
    cbuf[768 + c] = b1[c] - m1[c] * i1 + fb[c] * i1;
    float i2 = g2[c] * rsqrtf(v2[c] + 1e-5f);
    cbuf[1024 + c] = i2;
    cbuf[1280 + c] = b2[c] - m2[c] * i2 + balb[c] * i2;
}

// ---------------- bf16 copies of shared weights -----------------------------
__global__ __launch_bounds__(256) void k_wcopy(const float* fusw, const float* balw,
                                               ushort_t* fusw2b, ushort_t* balwb)
{
    int o = blockIdx.x, t = threadIdx.x;
    fusw2b[o * 256 + t] = f2bf(fusw[o * 512 + 256 + t]);
    balwb[o * 256 + t]  = f2bf(balw[o * 256 + t]);
}

// ---------------- edge dw3x3+BN+relu, bf16(x) copy, SE avg ------------------
__global__ __launch_bounds__(512) void k_edge(const float* x, const float* ew,
                                              const float* cbuf, ushort_t* A,
                                              float* avg)
{
    __shared__ __align__(16) ushort_t Xs[4096];   // [8h][64w][8c]
    __shared__ __align__(16) ushort_t Es[4096];
    int cg = blockIdx.x;
    int b = blockIdx.y;
    int t = threadIdx.x;
    int w = t & 63;
    int pl = t >> 6;                    // wave index = channel within group
    int c = cg * 8 + pl;
    const float* px = x + ((size_t)(b * 256 + c)) * HW;
    ushort_t* AX = A + ((size_t)(b * 64 + cg)) * PLSTRIDE;
    ushort_t* AE = A + ((size_t)(b * 64 + 32 + cg)) * PLSTRIDE;
    float wt[9];
    #pragma unroll
    for (int k = 0; k < 9; ++k) wt[k] = ew[c * 9 + k];
    float sE = cbuf[c], cE = cbuf[256 + c];
    bool wl = (w > 0), wrr = (w < 63);

    float p0l = 0.f, p0c = 0.f, p0r = 0.f;
    float p1l, p1c, p1r;
    p1c = px[w];
    p1l = wl ? px[w - 1] : 0.f;
    p1r = wrr ? px[w + 1] : 0.f;
    float s = 0.f;
    for (int hb = 0; hb < 8; ++hb) {
        #pragma unroll
        for (int hi = 0; hi < 8; ++hi) {
            int h = hb * 8 + hi;
            float p2l, p2c, p2r;
            if (h < 63) {
                const float* row = px + (h + 1) * 64;
                p2c = row[w];
                p2l = wl ? row[w - 1] : 0.f;
                p2r = wrr ? row[w + 1] : 0.f;
            } else {
                p2l = p2c = p2r = 0.f;
            }
            float a = p0l * wt[0] + p0c * wt[1] + p0r * wt[2]
                    + p1l * wt[3] + p1c * wt[4] + p1r * wt[5]
                    + p2l * wt[6] + p2c * wt[7] + p2r * wt[8];
            s += p1c;
            float v = a * sE + cE;
            Es[hi * 512 + w * 8 + pl] = f2bf(v > 0.f ? v : 0.f);
            Xs[hi * 512 + w * 8 + pl] = f2bf(p1c);
            p0l = p1l; p0c = p1c; p0r = p1r;
            p1l = p2l; p1c = p2c; p1r = p2r;
        }
        __syncthreads();
        {
            int hwg = (hb * 8 + pl) * 64 + w;
            uint4 vx = *(const uint4*)&Xs[pl * 512 + w * 8];
            uint4 ve = *(const uint4*)&Es[pl * 512 + w * 8];
            *(uint4*)(AX + (size_t)hwg * 8) = vx;
            *(uint4*)(AE + (size_t)hwg * 8) = ve;
        }
        __syncthreads();
    }
    #pragma unroll
    for (int off = 32; off > 0; off >>= 1) s += __shfl_down(s, off, 64);
    if ((t & 63) == 0) avg[b * 256 + c] = s * (1.0f / HW);
}

// ---------------- SE MLP + fold att into fusion_w[:, :256] (bf16) -----------
__global__ __launch_bounds__(256) void k_sefold(const float* avg, const float* fc1,
                                                const float* fc2, const float* fusw,
                                                ushort_t* w1b)
{
    int b = blockIdx.x, t = threadIdx.x;
    __shared__ float av[256];
    __shared__ float hid[16];
    av[t] = avg[b * 256 + t];
    __syncthreads();
    if (t < 16) {
        float h = 0.f;
        for (int c = 0; c < 256; ++c) h += av[c] * fc1[t * 256 + c];
        hid[t] = h > 0.f ? h : 0.f;
    }
    __syncthreads();
    float a = 0.f;
    #pragma unroll
    for (int j = 0; j < 16; ++j) a += hid[j] * fc2[t * 16 + j];
    float att = 1.0f / (1.0f + expf(-a));
    ushort_t* wout = w1b + (size_t)b * 65536;
    for (int o = 0; o < 256; ++o)
        wout[o * 256 + t] = f2bf(fusw[o * 512 + t] * att);
}

// ---------------- GEMM1: 64hw x 256o, K=512, barrier-free K-loop ------------
// Entire K staged to LDS up front (8 gld16/thread), ONE __syncthreads, then
// MFMA loop with register-double-buffered B and no further barriers.
__global__ __launch_bounds__(512) void k_gemm1(ushort_t* __restrict__ A,
                                               const ushort_t* __restrict__ w1b,
                                               const ushort_t* __restrict__ fusw2b,
                                               const float* __restrict__ cbuf)
{
    __shared__ __align__(16) ushort_t At[8][64 * 64];   // 64 KB
    int hw0 = blockIdx.x * 64;
    int b = blockIdx.y;
    int t = threadIdx.x;
    int lane = t & 63, wv = t >> 6;
    int quad = lane >> 4, l16 = lane & 15;
    int wr = wv >> 2, wc = wv & 3;      // 2 M x 4 N waves

    // ---- stage ALL K first (issue everything, drain once at the barrier) ---
    int mrow0 = wv * 8 + (lane >> 3);                    // 0..63
    int cswz = (lane & 7) ^ (mrow0 & 7);                 // pre-swizzled source
    const ushort_t* srcK = A + ((size_t)(b * 64 + cswz)) * PLSTRIDE
                             + ((size_t)(hw0 + mrow0)) * 8;
    #pragma unroll
    for (int kb = 0; kb < 8; ++kb)
        gld16(srcK + (size_t)(kb * 8) * PLSTRIDE, &At[kb][wv * 8 * 64]);

    v4f acc[2][4];
    #pragma unroll
    for (int i = 0; i < 2; ++i)
        #pragma unroll
        for (int j = 0; j < 4; ++j) acc[i][j] = (v4f){0.f, 0.f, 0.f, 0.f};

    const ushort_t* rowA[4];
    const ushort_t* rowB[4];
    int oo[4];
    #pragma unroll
    for (int nt = 0; nt < 4; ++nt) {
        int o = wc * 64 + nt * 16 + l16;
        oo[nt] = o;
        rowA[nt] = w1b + ((size_t)(b * 256 + o)) * 256;
        rowB[nt] = fusw2b + (size_t)o * 256;
    }

#define LDB1(dst, kbv) { \
    _Pragma("unroll") for (int ks2 = 0; ks2 < 2; ++ks2) { \
        int kg = (kbv) * 64 + ks2 * 32 + quad * 8; \
        _Pragma("unroll") for (int nt = 0; nt < 4; ++nt) { \
            dst[ks2][nt] = ((kbv) < 4) ? *(const v8s*)(rowA[nt] + kg) \
                                       : *(const v8s*)(rowB[nt] + (kg - 256)); \
        } } }

#define COMP1(kbv, bsrc) { \
    _Pragma("unroll") for (int ks2 = 0; ks2 < 2; ++ks2) { \
        v8s afr[2]; \
        _Pragma("unroll") for (int mt = 0; mt < 2; ++mt) { \
            int ml = wr * 32 + mt * 16 + l16; \
            int jj = (ks2 * 4 + quad) ^ (ml & 7); \
            afr[mt] = *(const v8s*)(&At[kbv][ml * 64 + jj * 8]); \
        } \
        _Pragma("unroll") for (int mt = 0; mt < 2; ++mt) \
            _Pragma("unroll") for (int nt = 0; nt < 4; ++nt) \
                acc[mt][nt] = __builtin_amdgcn_mfma_f32_16x16x32_bf16( \
                    afr[mt], bsrc[ks2][nt], acc[mt][nt], 0, 0, 0); \
    } }

    v8s bq0[2][4], bq1[2][4];
    LDB1(bq0, 0);
    __syncthreads();           // the ONLY barrier: drains all staging
    #pragma unroll 1
    for (int kb = 0; kb < 8; kb += 2) {
        LDB1(bq1, kb + 1);
        COMP1(kb, bq0);
        if (kb < 6) LDB1(bq0, kb + 2);
        COMP1(kb + 1, bq1);
    }
#undef LDB1
#undef COMP1

    // epilogue: bn1, write t1 into edge planes of OWN rows (all reads done)
    #pragma unroll
    for (int nt = 0; nt < 4; ++nt) {
        int o = oo[nt];
        float s1 = cbuf[512 + o], c1 = cbuf[768 + o];
        ushort_t* op = A + ((size_t)(b * 64 + 32 + (o >> 3))) * PLSTRIDE + (o & 7);
        #pragma unroll
        for (int mt = 0; mt < 2; ++mt)
            #pragma unroll
            for (int r = 0; r < 4; ++r) {
                int m = hw0 + wr * 32 + mt * 16 + quad * 4 + r;
                op[(size_t)m * 8] = f2bf(acc[mt][nt][r] * s1 + c1);
            }
    }
}

// ---------------- depthwise 3x3 on blocked layout: E-planes -> X-planes -----
__global__ __launch_bounds__(256) void k_dw2(ushort_t* A, const float* dfw)
{
    int h = blockIdx.x;
    int b = blockIdx.y;
    int t = threadIdx.x;
    int wc = t & 7;
    int cg = t >> 3;
    int c0 = cg * 8;
    int w0 = wc * 8;

    float acc[8][8];   // [w][ch]
    #pragma unroll
    for (int w = 0; w < 8; ++w)
        #pragma unroll
        for (int ch = 0; ch < 8; ++ch) acc[w][ch] = 0.f;

    const ushort_t* pE = A + ((size_t)(b * 64 + 32 + cg)) * PLSTRIDE;
    #pragma unroll
    for (int r = 0; r < 3; ++r) {
        int hh = h - 1 + r;
        if (hh < 0 || hh > 63) continue;
        float wtr[3][8];
        #pragma unroll
        for (int d = 0; d < 3; ++d)
            #pragma unroll
            for (int ch = 0; ch < 8; ++ch)
                wtr[d][ch] = dfw[(c0 + ch) * 9 + r * 3 + d];
        const ushort_t* row = pE + (size_t)(hh * 64) * 8;
        uint4 rv[10];
        #pragma unroll
        for (int j = 0; j < 10; ++j) {
            int col = w0 - 1 + j;
            if (col >= 0 && col < 64)
                rv[j] = *(const uint4*)(row + (size_t)col * 8);
            else
                rv[j] = (uint4){0u, 0u, 0u, 0u};
        }
        #pragma unroll
        for (int j = 0; j < 10; ++j) {
            unsigned int wd[4] = { rv[j].x, rv[j].y, rv[j].z, rv[j].w };
            float v[8];
            #pragma unroll
            for (int i = 0; i < 8; ++i)
                v[i] = bf2f((i & 1) ? (ushort_t)(wd[i >> 1] >> 16)
                                    : (ushort_t)(wd[i >> 1] & 0xffff));
            if (j <= 7)
                #pragma unroll
                for (int ch = 0; ch < 8; ++ch) acc[j][ch] += v[ch] * wtr[0][ch];
            if (j >= 1 && j <= 8)
                #pragma unroll
                for (int ch = 0; ch < 8; ++ch) acc[j - 1][ch] += v[ch] * wtr[1][ch];
            if (j >= 2)
                #pragma unroll
                for (int ch = 0; ch < 8; ++ch) acc[j - 2][ch] += v[ch] * wtr[2][ch];
        }
    }
    ushort_t* pX = A + ((size_t)(b * 64 + cg)) * PLSTRIDE + (size_t)(h * 64 + w0) * 8;
    #pragma unroll
    for (int w = 0; w < 8; ++w) {
        uint4 ov;
        ov.x = (unsigned int)f2bf(acc[w][0]) | ((unsigned int)f2bf(acc[w][1]) << 16);
        ov.y = (unsigned int)f2bf(acc[w][2]) | ((unsigned int)f2bf(acc[w][3]) << 16);
        ov.z = (unsigned int)f2bf(acc[w][4]) | ((unsigned int)f2bf(acc[w][5]) << 16);
        ov.w = (unsigned int)f2bf(acc[w][6]) | ((unsigned int)f2bf(acc[w][7]) << 16);
        *(uint4*)(pX + (size_t)w * 8) = ov;
    }
}

// ---------------- GEMM2: 128hw x 256o, K=256, barrier-free K-loop -----------
__global__ __launch_bounds__(512) void k_gemm2(ushort_t* __restrict__ A,
                                               const ushort_t* __restrict__ balwb)
{
    __shared__ __align__(16) ushort_t At[4][128 * 64];   // 64 KB
    int hw0 = blockIdx.x * 128;
    int b = blockIdx.y;
    int t = threadIdx.x;
    int lane = t & 63, wv = t >> 6;
    int quad = lane >> 4, l16 = lane & 15;
    int wr = wv >> 2, wc = wv & 3;

    // ---- stage ALL K first -------------------------------------------------
    int mrow0 = wv * 16 + (lane >> 3);                   // 0..127 (two halves)
    int cswz = (lane & 7) ^ (mrow0 & 7);
    const ushort_t* srcK = A + ((size_t)(b * 64 + cswz)) * PLSTRIDE
                             + ((size_t)(hw0 + mrow0)) * 8;
    #pragma unroll
    for (int kb = 0; kb < 4; ++kb) {
        const ushort_t* sp = srcK + (size_t)(kb * 8) * PLSTRIDE;
        gld16(sp, &At[kb][(wv * 16) * 64]);
        gld16(sp + 64, &At[kb][(wv * 16 + 8) * 64]);
    }

    v4f acc[4][4];
    #pragma unroll
    for (int i = 0; i < 4; ++i)
        #pragma unroll
        for (int j = 0; j < 4; ++j) acc[i][j] = (v4f){0.f, 0.f, 0.f, 0.f};

    const ushort_t* rowW[4];
    int oo[4];
    #pragma unroll
    for (int nt = 0; nt < 4; ++nt) {
        int o = wc * 64 + nt * 16 + l16;
        oo[nt] = o;
        rowW[nt] = balwb + (size_t)o * 256;
    }

#define LDB2(dst, kbv) { \
    _Pragma("unroll") for (int ks2 = 0; ks2 < 2; ++ks2) { \
        int kg = (kbv) * 64 + ks2 * 32 + quad * 8; \
        _Pragma("unroll") for (int nt = 0; nt < 4; ++nt) \
            dst[ks2][nt] = *(const v8s*)(rowW[nt] + kg); \
    } }

#define COMP2(kbv, bsrc) { \
    _Pragma("unroll") for (int ks2 = 0; ks2 < 2; ++ks2) { \
        v8s afr[4]; \
        _Pragma("unroll") for (int mt = 0; mt < 4; ++mt) { \
            int ml = wr * 64 + mt * 16 + l16; \
            int jj = (ks2 * 4 + quad) ^ (ml & 7); \
            afr[mt] = *(const v8s*)(&At[kbv][ml * 64 + jj * 8]); \
        } \
        _Pragma("unroll") for (int mt = 0; mt < 4; ++mt) \
            _Pragma("unroll") for (int nt = 0; nt < 4; ++nt) \
                acc[mt][nt] = __builtin_amdgcn_mfma_f32_16x16x32_bf16( \
                    afr[mt], bsrc[ks2][nt], acc[mt][nt], 0, 0, 0); \
    } }

    v8s bq0[2][4], bq1[2][4];
    LDB2(bq0, 0);
    __syncthreads();           // the ONLY barrier
    #pragma unroll 1
    for (int kb = 0; kb < 4; kb += 2) {
        LDB2(bq1, kb + 1);
        COMP2(kb, bq0);
        if (kb < 2) LDB2(bq0, kb + 2);
        COMP2(kb + 1, bq1);
    }
#undef LDB2
#undef COMP2

    #pragma unroll
    for (int nt = 0; nt < 4; ++nt) {
        int o = oo[nt];
        ushort_t* op = A + ((size_t)(b * 64 + 32 + (o >> 3))) * PLSTRIDE + (o & 7);
        #pragma unroll
        for (int mt = 0; mt < 4; ++mt)
            #pragma unroll
            for (int r = 0; r < 4; ++r) {
                int m = hw0 + wr * 64 + mt * 16 + quad * 4 + r;
                op[(size_t)m * 8] = f2bf(acc[mt][nt][r]);
            }
    }
}

// ---------------- final: blocked->NCHW transpose + BN2 + gate by x ----------
__global__ __launch_bounds__(256) void k_final(const ushort_t* A, const float* x,
                                               const float* cbuf, float* out)
{
    __shared__ float Lt[64 * 65];
    int bid = blockIdx.x;
    int b = bid >> 8;
    int rem = bid & 255;
    int hw0 = (rem >> 2) * 64;
    int c0 = (rem & 3) * 64;
    int t = threadIdx.x;
    #pragma unroll
    for (int r = 0; r < 2; ++r) {
        int idx = r * 256 + t;
        int hwl = idx >> 3;
        int cq = idx & 7;
        uint4 v = *(const uint4*)(A + ((size_t)(b * 64 + 32 + (c0 >> 3) + cq)) * PLSTRIDE
                                    + (size_t)(hw0 + hwl) * 8);
        unsigned int wd[4] = { v.x, v.y, v.z, v.w };
        #pragma unroll
        for (int j = 0; j < 8; ++j) {
            ushort_t u = (j & 1) ? (ushort_t)(wd[j >> 1] >> 16) : (ushort_t)(wd[j >> 1] & 0xffff);
            Lt[(cq * 8 + j) * 65 + hwl] = bf2f(u);
        }
    }
    __syncthreads();
    int hw_l = t & 63;
    int c_l0 = t >> 6;
    #pragma unroll
    for (int j = 0; j < 16; ++j) {
        int c_l = c_l0 * 16 + j;
        int c = c0 + c_l;
        float s2 = cbuf[1024 + c], c2 = cbuf[1280 + c];
        size_t g = ((size_t)b * 256 + c) * HW + hw0 + hw_l;
        float xv = x[g];
        out[g] = (Lt[c_l * 65 + hw_l] * s2 + c2) * xv;
    }
}

extern "C" void kernel_launch(void* const* d_in, const int* in_sizes, int n_in,
                              void* d_out, int out_size, void* d_ws, size_t ws_size,
                              hipStream_t stream)
{
    const float* x    = (const float*)d_in[0];
    const float* ew   = (const float*)d_in[1];
    const float* fc1  = (const float*)d_in[6];
    const float* fc2  = (const float*)d_in[7];
    const float* fusw = (const float*)d_in[8];
    const float* dfw  = (const float*)d_in[14];
    const float* balw = (const float*)d_in[15];
    float* out = (float*)d_out;

    char* ws = (char*)d_ws;
    ushort_t* A      = (ushort_t*)(ws);                 // 134217728 B
    ushort_t* w1b    = (ushort_t*)(ws + 134217728);     // 4 MiB
    ushort_t* fusw2b = (ushort_t*)(ws + 138412032);     // 128 KiB
    ushort_t* balwb  = (ushort_t*)(ws + 138543104);     // 128 KiB
    float*    avg    = (float*)(ws + 138674176);        // 32 KiB
    float*    cbuf   = (float*)(ws + 138706944);        // 6 KiB

    k_consts<<<1, 256, 0, stream>>>((const float*)d_in[2], (const float*)d_in[3],
                                    (const float*)d_in[4], (const float*)d_in[5],
                                    (const float*)d_in[9],
                                    (const float*)d_in[10], (const float*)d_in[11],
                                    (const float*)d_in[12], (const float*)d_in[13],
                                    (const float*)d_in[16],
                                    (const float*)d_in[17], (const float*)d_in[18],
                                    (const float*)d_in[19], (const float*)d_in[20],
                                    cbuf);
    k_wcopy<<<256, 256, 0, stream>>>(fusw, balw, fusw2b, balwb);
    k_edge<<<dim3(32, 32), 512, 0, stream>>>(x, ew, cbuf, A, avg);
    k_sefold<<<32, 256, 0, stream>>>(avg, fc1, fc2, fusw, w1b);
    k_gemm1<<<dim3(64, 32), 512, 0, stream>>>(A, w1b, fusw2b, cbuf);
    k_dw2<<<dim3(64, 32), 256, 0, stream>>>(A, dfw);
    k_gemm2<<<dim3(32, 32), 512, 0, stream>>>(A, balwb);
    k_final<<<8192, 256, 0, stream>>>(A, x, cbuf, out);
}

// Round 4
// 538.469 us; speedup vs baseline: 1.2043x; 1.2043x over previous
//
#include <hip/hip_runtime.h>
#include <math.h>

#define HW 4096
#define PLSTRIDE ((size_t)HW * 8)   // elements per 8-channel plane of A

typedef unsigned short ushort_t;
typedef short v8s __attribute__((ext_vector_type(8)));
typedef float v4f __attribute__((ext_vector_type(4)));

__device__ __forceinline__ float bf2f(ushort_t u) {
    union { unsigned int i; float f; } v; v.i = ((unsigned int)u) << 16; return v.f;
}
__device__ __forceinline__ ushort_t f2bf(float f) {
    unsigned int x = __float_as_uint(f);
    x += 0x7fffu + ((x >> 16) & 1u);   // RNE
    return (ushort_t)(x >> 16);
}

// async global->LDS, 16B per lane; LDS dest = wave-uniform base + lane*16
__device__ __forceinline__ void gld16(const ushort_t* g, ushort_t* l) {
    __builtin_amdgcn_global_load_lds(
        (__attribute__((address_space(1))) void*)g,
        (__attribute__((address_space(3))) void*)l, 16, 0, 0);
}

// ---------------- per-channel constants -------------------------------------
// cbuf layout (floats): [0]=sE [256]=cE [512]=s1 [768]=c1 [1024]=s2 [1280]=c2
__global__ __launch_bounds__(256) void k_consts(
    const float* eg, const float* ebt, const float* em, const float* ev,
    const float* fb,
    const float* g1, const float* b1, const float* m1, const float* v1,
    const float* balb,
    const float* g2, const float* b2, const float* m2, const float* v2,
    float* cbuf)
{
    int c = threadIdx.x;
    float iE = eg[c] * rsqrtf(ev[c] + 1e-5f);
    cbuf[c]       = iE;
    cbuf[256 + c] = ebt[c] - em[c] * iE;
    float i1 = g1[c] * rsqrtf(v1[c] + 1e-5f);
    cbuf[512 + c] = i1;
    cbuf[768 + c] = b1[c] - m1[c] * i1 + fb[c] * i1;
    float i2 = g2[c] * rsqrtf(v2[c] + 1e-5f);
    cbuf[1024 + c] = i2;
    cbuf[1280 + c] = b2[c] - m2[c] * i2 + balb[c] * i2;
}

// ---------------- bf16 copies of shared weights -----------------------------
__global__ __launch_bounds__(256) void k_wcopy(const float* fusw, const float* balw,
                                               ushort_t* fusw2b, ushort_t* balwb)
{
    int o = blockIdx.x, t = threadIdx.x;
    fusw2b[o * 256 + t] = f2bf(fusw[o * 512 + 256 + t]);
    balwb[o * 256 + t]  = f2bf(balw[o * 256 + t]);
}

// ---------------- edge dw3x3+BN+relu, bf16(x) copy, SE avg ------------------
__global__ __launch_bounds__(512) void k_edge(const float* x, const float* ew,
                                              const float* cbuf, ushort_t* A,
                                              float* avg)
{
    __shared__ __align__(16) ushort_t Xs[4096];   // [8h][64w][8c]
    __shared__ __align__(16) ushort_t Es[4096];
    int cg = blockIdx.x;
    int b = blockIdx.y;
    int t = threadIdx.x;
    int w = t & 63;
    int pl = t >> 6;                    // wave index = channel within group
    int c = cg * 8 + pl;
    const float* px = x + ((size_t)(b * 256 + c)) * HW;
    ushort_t* AX = A + ((size_t)(b * 64 + cg)) * PLSTRIDE;
    ushort_t* AE = A + ((size_t)(b * 64 + 32 + cg)) * PLSTRIDE;
    float wt[9];
    #pragma unroll
    for (int k = 0; k < 9; ++k) wt[k] = ew[c * 9 + k];
    float sE = cbuf[c], cE = cbuf[256 + c];
    bool wl = (w > 0), wrr = (w < 63);

    float p0l = 0.f, p0c = 0.f, p0r = 0.f;
    float p1l, p1c, p1r;
    p1c = px[w];
    p1l = wl ? px[w - 1] : 0.f;
    p1r = wrr ? px[w + 1] : 0.f;
    float s = 0.f;
    for (int hb = 0; hb < 8; ++hb) {
        #pragma unroll
        for (int hi = 0; hi < 8; ++hi) {
            int h = hb * 8 + hi;
            float p2l, p2c, p2r;
            if (h < 63) {
                const float* row = px + (h + 1) * 64;
                p2c = row[w];
                p2l = wl ? row[w - 1] : 0.f;
                p2r = wrr ? row[w + 1] : 0.f;
            } else {
                p2l = p2c = p2r = 0.f;
            }
            float a = p0l * wt[0] + p0c * wt[1] + p0r * wt[2]
                    + p1l * wt[3] + p1c * wt[4] + p1r * wt[5]
                    + p2l * wt[6] + p2c * wt[7] + p2r * wt[8];
            s += p1c;
            float v = a * sE + cE;
            Es[hi * 512 + w * 8 + pl] = f2bf(v > 0.f ? v : 0.f);
            Xs[hi * 512 + w * 8 + pl] = f2bf(p1c);
            p0l = p1l; p0c = p1c; p0r = p1r;
            p1l = p2l; p1c = p2c; p1r = p2r;
        }
        __syncthreads();
        {
            int hwg = (hb * 8 + pl) * 64 + w;
            uint4 vx = *(const uint4*)&Xs[pl * 512 + w * 8];
            uint4 ve = *(const uint4*)&Es[pl * 512 + w * 8];
            *(uint4*)(AX + (size_t)hwg * 8) = vx;
            *(uint4*)(AE + (size_t)hwg * 8) = ve;
        }
        __syncthreads();
    }
    #pragma unroll
    for (int off = 32; off > 0; off >>= 1) s += __shfl_down(s, off, 64);
    if ((t & 63) == 0) avg[b * 256 + c] = s * (1.0f / HW);
}

// ---------------- SE MLP + fold att into fusion_w[:, :256] (bf16) -----------
__global__ __launch_bounds__(256) void k_sefold(const float* avg, const float* fc1,
                                                const float* fc2, const float* fusw,
                                                ushort_t* w1b)
{
    int b = blockIdx.x, t = threadIdx.x;
    __shared__ float av[256];
    __shared__ float hid[16];
    av[t] = avg[b * 256 + t];
    __syncthreads();
    if (t < 16) {
        float h = 0.f;
        for (int c = 0; c < 256; ++c) h += av[c] * fc1[t * 256 + c];
        hid[t] = h > 0.f ? h : 0.f;
    }
    __syncthreads();
    float a = 0.f;
    #pragma unroll
    for (int j = 0; j < 16; ++j) a += hid[j] * fc2[t * 16 + j];
    float att = 1.0f / (1.0f + expf(-a));
    ushort_t* wout = w1b + (size_t)b * 65536;
    for (int o = 0; o < 256; ++o)
        wout[o * 256 + t] = f2bf(fusw[o * 512 + t] * att);
}

// ---------------- GEMM1: 128hw x 256o (full N, race-free), K=512 ------------
// m97-style: BOTH operands gld16-staged to LDS (coalesced, XOR-swizzled),
// 2 barriers per K-step. 512 thr = 8 waves (2M x 4N). In-place t1 epilogue.
__global__ __launch_bounds__(512, 4) void k_gemm1(ushort_t* __restrict__ A,
                                                  const ushort_t* __restrict__ w1b,
                                                  const ushort_t* __restrict__ fusw2b,
                                                  const float* __restrict__ cbuf)
{
    __shared__ __align__(16) ushort_t At[128 * 64];   // 16 KB
    __shared__ __align__(16) ushort_t Bt[256 * 64];   // 32 KB
    int bid = blockIdx.x;
    int orig = (bid & 7) * 128 + (bid >> 3);          // XCD-chunked remap
    int b = orig >> 5;
    int hw0 = (orig & 31) * 128;
    int t = threadIdx.x;
    int lane = t & 63, wv = t >> 6;
    int quad = lane >> 4, l16 = lane & 15;
    int wr = wv >> 2, wc = wv & 3;                    // 2M x 4N waves
    int srow = lane >> 3, kch = lane & 7;

    v4f acc[4][4];
    #pragma unroll
    for (int i = 0; i < 4; ++i)
        #pragma unroll
        for (int j = 0; j < 4; ++j) acc[i][j] = (v4f){0.f, 0.f, 0.f, 0.f};

    for (int kb = 0; kb < 8; ++kb) {
        __syncthreads();
        // stage A-tile [128m][64k]: 2 rounds, pre-swizzled source chunk
        #pragma unroll
        for (int r = 0; r < 2; ++r) {
            int mrow = wv * 8 + r * 64 + srow;
            int csw = kch ^ (mrow & 7);
            gld16(A + ((size_t)(b * 64 + kb * 8 + csw)) * PLSTRIDE
                    + (size_t)(hw0 + mrow) * 8,
                  &At[(wv * 8 + r * 64) * 64]);
        }
        // stage B-tile [256o][64k]: 4 rounds from w1b / fusw2b rows
        #pragma unroll
        for (int r = 0; r < 4; ++r) {
            int orow = wv * 8 + r * 64 + srow;
            int kc2 = kch ^ (orow & 7);
            const ushort_t* bs = (kb < 4)
                ? (w1b + ((size_t)(b * 256 + orow)) * 256 + kb * 64 + kc2 * 8)
                : (fusw2b + ((size_t)orow) * 256 + (kb - 4) * 64 + kc2 * 8);
            gld16(bs, &Bt[(wv * 8 + r * 64) * 64]);
        }
        __syncthreads();
        #pragma unroll
        for (int ks2 = 0; ks2 < 2; ++ks2) {
            v8s afr[4], bfr[4];
            #pragma unroll
            for (int mt = 0; mt < 4; ++mt) {
                int ml = wr * 64 + mt * 16 + l16;
                int jj = (ks2 * 4 + quad) ^ (ml & 7);
                afr[mt] = *(const v8s*)(&At[ml * 64 + jj * 8]);
            }
            #pragma unroll
            for (int nt = 0; nt < 4; ++nt) {
                int ol = wc * 64 + nt * 16 + l16;
                int jj = (ks2 * 4 + quad) ^ (ol & 7);
                bfr[nt] = *(const v8s*)(&Bt[ol * 64 + jj * 8]);
            }
            #pragma unroll
            for (int mt = 0; mt < 4; ++mt)
                #pragma unroll
                for (int nt = 0; nt < 4; ++nt)
                    acc[mt][nt] = __builtin_amdgcn_mfma_f32_16x16x32_bf16(
                        afr[mt], bfr[nt], acc[mt][nt], 0, 0, 0);
        }
    }

    // epilogue: bn1, write t1 into edge planes of OWN rows (race-free)
    #pragma unroll
    for (int nt = 0; nt < 4; ++nt) {
        int o = wc * 64 + nt * 16 + l16;
        float s1 = cbuf[512 + o], c1 = cbuf[768 + o];
        ushort_t* op = A + ((size_t)(b * 64 + 32 + (o >> 3))) * PLSTRIDE + (o & 7);
        #pragma unroll
        for (int mt = 0; mt < 4; ++mt)
            #pragma unroll
            for (int r = 0; r < 4; ++r) {
                int m = hw0 + wr * 64 + mt * 16 + quad * 4 + r;
                op[(size_t)m * 8] = f2bf(acc[mt][nt][r] * s1 + c1);
            }
    }
}

// ---------------- depthwise 3x3: E-planes -> X-planes, shfl-stencil ---------
// wave = 64 w-columns of one channel-group plane; fully coalesced 16B loads,
// neighbors via __shfl, no LDS, no barriers. grid (8 cgq, 32 b, 2 h-halves).
__global__ __launch_bounds__(256) void k_dw2(ushort_t* __restrict__ A,
                                             const float* __restrict__ dfw)
{
    int t = threadIdx.x;
    int w = t & 63;
    int pl = t >> 6;
    int cg = blockIdx.x * 4 + pl;
    int b = blockIdx.y;
    int h0 = blockIdx.z * 32;
    const ushort_t* pE = A + ((size_t)(b * 64 + 32 + cg)) * PLSTRIDE;
    ushort_t* pX = A + ((size_t)(b * 64 + cg)) * PLSTRIDE;
    float wt[3][3][8];
    #pragma unroll
    for (int r = 0; r < 3; ++r)
        #pragma unroll
        for (int d = 0; d < 3; ++d)
            #pragma unroll
            for (int ch = 0; ch < 8; ++ch)
                wt[r][d][ch] = dfw[(cg * 8 + ch) * 9 + r * 3 + d];
    bool wl = (w > 0), wrr = (w < 63);

    uint4 rm, rc, rp;
    rm = (h0 > 0) ? *(const uint4*)(pE + (size_t)((h0 - 1) * 64 + w) * 8)
                  : (uint4){0u, 0u, 0u, 0u};
    rc = *(const uint4*)(pE + (size_t)(h0 * 64 + w) * 8);

#define DWROW(v, r) { \
    unsigned int cx0 = v.x, cx1 = v.y, cx2 = v.z, cx3 = v.w; \
    unsigned int lx0 = __shfl_up(cx0, 1, 64), lx1 = __shfl_up(cx1, 1, 64); \
    unsigned int lx2 = __shfl_up(cx2, 1, 64), lx3 = __shfl_up(cx3, 1, 64); \
    unsigned int rx0 = __shfl_down(cx0, 1, 64), rx1 = __shfl_down(cx1, 1, 64); \
    unsigned int rx2 = __shfl_down(cx2, 1, 64), rx3 = __shfl_down(cx3, 1, 64); \
    unsigned int cw[4] = { cx0, cx1, cx2, cx3 }; \
    unsigned int lw[4] = { lx0, lx1, lx2, lx3 }; \
    unsigned int rw[4] = { rx0, rx1, rx2, rx3 }; \
    _Pragma("unroll") for (int ch = 0; ch < 8; ++ch) { \
        float fC = bf2f((ch & 1) ? (ushort_t)(cw[ch >> 1] >> 16) \
                                 : (ushort_t)(cw[ch >> 1] & 0xffff)); \
        float fL = wl ? bf2f((ch & 1) ? (ushort_t)(lw[ch >> 1] >> 16) \
                                      : (ushort_t)(lw[ch >> 1] & 0xffff)) : 0.f; \
        float fR = wrr ? bf2f((ch & 1) ? (ushort_t)(rw[ch >> 1] >> 16) \
                                       : (ushort_t)(rw[ch >> 1] & 0xffff)) : 0.f; \
        acc[ch] += fL * wt[r][0][ch] + fC * wt[r][1][ch] + fR * wt[r][2][ch]; \
    } }

    for (int s = 0; s < 32; ++s) {
        int h = h0 + s;
        rp = (h + 1 < 64) ? *(const uint4*)(pE + (size_t)((h + 1) * 64 + w) * 8)
                          : (uint4){0u, 0u, 0u, 0u};
        float acc[8];
        #pragma unroll
        for (int ch = 0; ch < 8; ++ch) acc[ch] = 0.f;
        DWROW(rm, 0);
        DWROW(rc, 1);
        DWROW(rp, 2);
        uint4 ov;
        ov.x = (unsigned int)f2bf(acc[0]) | ((unsigned int)f2bf(acc[1]) << 16);
        ov.y = (unsigned int)f2bf(acc[2]) | ((unsigned int)f2bf(acc[3]) << 16);
        ov.z = (unsigned int)f2bf(acc[4]) | ((unsigned int)f2bf(acc[5]) << 16);
        ov.w = (unsigned int)f2bf(acc[6]) | ((unsigned int)f2bf(acc[7]) << 16);
        *(uint4*)(pX + (size_t)(h * 64 + w) * 8) = ov;
        rm = rc; rc = rp;
    }
#undef DWROW
}

// ---------------- GEMM2: 128hw x 256o (full N), K=256, m97-style ------------
__global__ __launch_bounds__(512, 4) void k_gemm2(ushort_t* __restrict__ A,
                                                  const ushort_t* __restrict__ balwb)
{
    __shared__ __align__(16) ushort_t At[128 * 64];   // 16 KB
    __shared__ __align__(16) ushort_t Bt[256 * 64];   // 32 KB
    int bid = blockIdx.x;
    int orig = (bid & 7) * 128 + (bid >> 3);
    int b = orig >> 5;
    int hw0 = (orig & 31) * 128;
    int t = threadIdx.x;
    int lane = t & 63, wv = t >> 6;
    int quad = lane >> 4, l16 = lane & 15;
    int wr = wv >> 2, wc = wv & 3;
    int srow = lane >> 3, kch = lane & 7;

    v4f acc[4][4];
    #pragma unroll
    for (int i = 0; i < 4; ++i)
        #pragma unroll
        for (int j = 0; j < 4; ++j) acc[i][j] = (v4f){0.f, 0.f, 0.f, 0.f};

    for (int kb = 0; kb < 4; ++kb) {
        __syncthreads();
        #pragma unroll
        for (int r = 0; r < 2; ++r) {
            int mrow = wv * 8 + r * 64 + srow;
            int csw = kch ^ (mrow & 7);
            gld16(A + ((size_t)(b * 64 + kb * 8 + csw)) * PLSTRIDE
                    + (size_t)(hw0 + mrow) * 8,
                  &At[(wv * 8 + r * 64) * 64]);
        }
        #pragma unroll
        for (int r = 0; r < 4; ++r) {
            int orow = wv * 8 + r * 64 + srow;
            int kc2 = kch ^ (orow & 7);
            gld16(balwb + ((size_t)orow) * 256 + kb * 64 + kc2 * 8,
                  &Bt[(wv * 8 + r * 64) * 64]);
        }
        __syncthreads();
        #pragma unroll
        for (int ks2 = 0; ks2 < 2; ++ks2) {
            v8s afr[4], bfr[4];
            #pragma unroll
            for (int mt = 0; mt < 4; ++mt) {
                int ml = wr * 64 + mt * 16 + l16;
                int jj = (ks2 * 4 + quad) ^ (ml & 7);
                afr[mt] = *(const v8s*)(&At[ml * 64 + jj * 8]);
            }
            #pragma unroll
            for (int nt = 0; nt < 4; ++nt) {
                int ol = wc * 64 + nt * 16 + l16;
                int jj = (ks2 * 4 + quad) ^ (ol & 7);
                bfr[nt] = *(const v8s*)(&Bt[ol * 64 + jj * 8]);
            }
            #pragma unroll
            for (int mt = 0; mt < 4; ++mt)
                #pragma unroll
                for (int nt = 0; nt < 4; ++nt)
                    acc[mt][nt] = __builtin_amdgcn_mfma_f32_16x16x32_bf16(
                        afr[mt], bfr[nt], acc[mt][nt], 0, 0, 0);
        }
    }

    #pragma unroll
    for (int nt = 0; nt < 4; ++nt) {
        int o = wc * 64 + nt * 16 + l16;
        ushort_t* op = A + ((size_t)(b * 64 + 32 + (o >> 3))) * PLSTRIDE + (o & 7);
        #pragma unroll
        for (int mt = 0; mt < 4; ++mt)
            #pragma unroll
            for (int r = 0; r < 4; ++r) {
                int m = hw0 + wr * 64 + mt * 16 + quad * 4 + r;
                op[(size_t)m * 8] = f2bf(acc[mt][nt][r]);
            }
    }
}

// ---------------- final: blocked->NCHW transpose + BN2 + gate by x ----------
__global__ __launch_bounds__(256) void k_final(const ushort_t* A, const float* x,
                                               const float* cbuf, float* out)
{
    __shared__ float Lt[64 * 65];
    int bid = blockIdx.x;
    int b = bid >> 8;
    int rem = bid & 255;
    int hw0 = (rem >> 2) * 64;
    int c0 = (rem & 3) * 64;
    int t = threadIdx.x;
    #pragma unroll
    for (int r = 0; r < 2; ++r) {
        int idx = r * 256 + t;
        int cq = idx >> 6;          // plane within the 64-ch group
        int hwl = idx & 63;         // lanes sweep hw -> coalesced 1KB reads
        uint4 v = *(const uint4*)(A + ((size_t)(b * 64 + 32 + (c0 >> 3) + cq)) * PLSTRIDE
                                    + (size_t)(hw0 + hwl) * 8);
        unsigned int wd[4] = { v.x, v.y, v.z, v.w };
        #pragma unroll
        for (int j = 0; j < 8; ++j) {
            ushort_t u = (j & 1) ? (ushort_t)(wd[j >> 1] >> 16) : (ushort_t)(wd[j >> 1] & 0xffff);
            Lt[(cq * 8 + j) * 65 + hwl] = bf2f(u);
        }
    }
    __syncthreads();
    int hw_l = t & 63;
    int c_l0 = t >> 6;
    #pragma unroll
    for (int j = 0; j < 16; ++j) {
        int c_l = c_l0 * 16 + j;
        int c = c0 + c_l;
        float s2 = cbuf[1024 + c], c2 = cbuf[1280 + c];
        size_t g = ((size_t)b * 256 + c) * HW + hw0 + hw_l;
        float xv = x[g];
        out[g] = (Lt[c_l * 65 + hw_l] * s2 + c2) * xv;
    }
}

extern "C" void kernel_launch(void* const* d_in, const int* in_sizes, int n_in,
                              void* d_out, int out_size, void* d_ws, size_t ws_size,
                              hipStream_t stream)
{
    const float* x    = (const float*)d_in[0];
    const float* ew   = (const float*)d_in[1];
    const float* fc1  = (const float*)d_in[6];
    const float* fc2  = (const float*)d_in[7];
    const float* fusw = (const float*)d_in[8];
    const float* dfw  = (const float*)d_in[14];
    const float* balw = (const float*)d_in[15];
    float* out = (float*)d_out;

    char* ws = (char*)d_ws;
    ushort_t* A      = (ushort_t*)(ws);                 // 134217728 B
    ushort_t* w1b    = (ushort_t*)(ws + 134217728);     // 4 MiB
    ushort_t* fusw2b = (ushort_t*)(ws + 138412032);     // 128 KiB
    ushort_t* balwb  = (ushort_t*)(ws + 138543104);     // 128 KiB
    float*    avg    = (float*)(ws + 138674176);        // 32 KiB
    float*    cbuf   = (float*)(ws + 138706944);        // 6 KiB

    k_consts<<<1, 256, 0, stream>>>((const float*)d_in[2], (const float*)d_in[3],
                                    (const float*)d_in[4], (const float*)d_in[5],
                                    (const float*)d_in[9],
                                    (const float*)d_in[10], (const float*)d_in[11],
                                    (const float*)d_in[12], (const float*)d_in[13],
                                    (const float*)d_in[16],
                                    (const float*)d_in[17], (const float*)d_in[18],
                                    (const float*)d_in[19], (const float*)d_in[20],
                                    cbuf);
    k_wcopy<<<256, 256, 0, stream>>>(fusw, balw, fusw2b, balwb);
    k_edge<<<dim3(32, 32), 512, 0, stream>>>(x, ew, cbuf, A, avg);
    k_sefold<<<32, 256, 0, stream>>>(avg, fc1, fc2, fusw, w1b);
    k_gemm1<<<1024, 512, 0, stream>>>(A, w1b, fusw2b, cbuf);
    k_dw2<<<dim3(8, 32, 2), 256, 0, stream>>>(A, dfw);
    k_gemm2<<<1024, 512, 0, stream>>>(A, balwb);
    k_final<<<8192, 256, 0, stream>>>(A, x, cbuf, out);
}

// Round 5
// 534.788 us; speedup vs baseline: 1.2126x; 1.0069x over previous
//
#include <hip/hip_runtime.h>
#include <math.h>

#define HW 4096
#define PLSTRIDE ((size_t)HW * 8)   // elements per 8-channel plane of A

typedef unsigned short ushort_t;
typedef short v8s __attribute__((ext_vector_type(8)));
typedef float v4f __attribute__((ext_vector_type(4)));

__device__ __forceinline__ float bf2f(ushort_t u) {
    union { unsigned int i; float f; } v; v.i = ((unsigned int)u) << 16; return v.f;
}
__device__ __forceinline__ ushort_t f2bf(float f) {
    unsigned int x = __float_as_uint(f);
    x += 0x7fffu + ((x >> 16) & 1u);   // RNE
    return (ushort_t)(x >> 16);
}

// async global->LDS, 16B per lane; LDS dest = wave-uniform base + lane*16
__device__ __forceinline__ void gld16(const ushort_t* g, ushort_t* l) {
    __builtin_amdgcn_global_load_lds(
        (__attribute__((address_space(1))) void*)g,
        (__attribute__((address_space(3))) void*)l, 16, 0, 0);
}

// ---------------- per-channel constants -------------------------------------
// cbuf layout (floats): [0]=sE [256]=cE [512]=s1 [768]=c1 [1024]=s2 [1280]=c2
__global__ __launch_bounds__(256) void k_consts(
    const float* eg, const float* ebt, const float* em, const float* ev,
    const float* fb,
    const float* g1, const float* b1, const float* m1, const float* v1,
    const float* balb,
    const float* g2, const float* b2, const float* m2, const float* v2,
    float* cbuf)
{
    int c = threadIdx.x;
    float iE = eg[c] * rsqrtf(ev[c] + 1e-5f);
    cbuf[c]       = iE;
    cbuf[256 + c] = ebt[c] - em[c] * iE;
    float i1 = g1[c] * rsqrtf(v1[c] + 1e-5f);
    cbuf[512 + c] = i1;
    cbuf[768 + c] = b1[c] - m1[c] * i1 + fb[c] * i1;
    float i2 = g2[c] * rsqrtf(v2[c] + 1e-5f);
    cbuf[1024 + c] = i2;
    cbuf[1280 + c] = b2[c] - m2[c] * i2 + balb[c] * i2;
}

// ---------------- bf16 copies of shared weights -----------------------------
__global__ __launch_bounds__(256) void k_wcopy(const float* fusw, const float* balw,
                                               ushort_t* fusw2b, ushort_t* balwb)
{
    int o = blockIdx.x, t = threadIdx.x;
    fusw2b[o * 256 + t] = f2bf(fusw[o * 512 + 256 + t]);
    balwb[o * 256 + t]  = f2bf(balw[o * 256 + t]);
}

// ---------------- edge dw3x3+BN+relu, bf16(x) copy, SE avg ------------------
// LDS transpose layout [j][ch][w] u32 (h-pairs packed): BOTH write and read
// sides are lane-contiguous (2 lanes/bank = free), vs old [w][ch] b16 scatter
// that was an 8-way conflict on every write (6.3M conflicts measured).
// Superrounds of 16 h: 8 barriers total, 128 conflict-free DS ops/thread.
__global__ __launch_bounds__(512) void k_edge(const float* x, const float* ew,
                                              const float* cbuf, ushort_t* A,
                                              float* avg)
{
    __shared__ unsigned int Xs[8][8][64];   // [hpair j][ch][w], 16 KB
    __shared__ unsigned int Es[8][8][64];
    int cg = blockIdx.x;
    int b = blockIdx.y;
    int t = threadIdx.x;
    int w = t & 63;
    int pl = t >> 6;                    // wave index = channel within group
    int c = cg * 8 + pl;
    const float* px = x + ((size_t)(b * 256 + c)) * HW;
    ushort_t* AX = A + ((size_t)(b * 64 + cg)) * PLSTRIDE;
    ushort_t* AE = A + ((size_t)(b * 64 + 32 + cg)) * PLSTRIDE;
    float wt[9];
    #pragma unroll
    for (int k = 0; k < 9; ++k) wt[k] = ew[c * 9 + k];
    float sE = cbuf[c], cE = cbuf[256 + c];
    bool wl = (w > 0), wrr = (w < 63);

    float p0l = 0.f, p0c = 0.f, p0r = 0.f;
    float p1l, p1c, p1r;
    p1c = px[w];
    p1l = wl ? px[w - 1] : 0.f;
    p1r = wrr ? px[w + 1] : 0.f;
    float s = 0.f;
    unsigned int xprev = 0, eprev = 0;
    for (int sr = 0; sr < 4; ++sr) {
        #pragma unroll
        for (int hl = 0; hl < 16; ++hl) {
            int h = sr * 16 + hl;
            float p2l, p2c, p2r;
            if (h < 63) {
                const float* row = px + (h + 1) * 64;
                p2c = row[w];
                p2l = wl ? row[w - 1] : 0.f;
                p2r = wrr ? row[w + 1] : 0.f;
            } else {
                p2l = p2c = p2r = 0.f;
            }
            float a = p0l * wt[0] + p0c * wt[1] + p0r * wt[2]
                    + p1l * wt[3] + p1c * wt[4] + p1r * wt[5]
                    + p2l * wt[6] + p2c * wt[7] + p2r * wt[8];
            s += p1c;
            float v = a * sE + cE;
            unsigned int eb = (unsigned int)f2bf(v > 0.f ? v : 0.f);
            unsigned int xb = (unsigned int)f2bf(p1c);
            if (hl & 1) {
                Es[hl >> 1][pl][w] = eprev | (eb << 16);
                Xs[hl >> 1][pl][w] = xprev | (xb << 16);
            } else {
                eprev = eb; xprev = xb;
            }
            p0l = p1l; p0c = p1c; p0r = p1r;
            p1l = p2l; p1c = p2c; p1r = p2r;
        }
        __syncthreads();
        {
            // flush: thread (pl,w) -> points h = sr*16 + 2*pl (+1)
            unsigned int xr[8], er[8];
            #pragma unroll
            for (int ch = 0; ch < 8; ++ch) {
                xr[ch] = Xs[pl][ch][w];
                er[ch] = Es[pl][ch][w];
            }
            uint4 x0, x1, e0, e1;
            x0.x = (xr[0] & 0xffffu) | (xr[1] << 16);
            x0.y = (xr[2] & 0xffffu) | (xr[3] << 16);
            x0.z = (xr[4] & 0xffffu) | (xr[5] << 16);
            x0.w = (xr[6] & 0xffffu) | (xr[7] << 16);
            x1.x = (xr[0] >> 16) | (xr[1] & 0xffff0000u);
            x1.y = (xr[2] >> 16) | (xr[3] & 0xffff0000u);
            x1.z = (xr[4] >> 16) | (xr[5] & 0xffff0000u);
            x1.w = (xr[6] >> 16) | (xr[7] & 0xffff0000u);
            e0.x = (er[0] & 0xffffu) | (er[1] << 16);
            e0.y = (er[2] & 0xffffu) | (er[3] << 16);
            e0.z = (er[4] & 0xffffu) | (er[5] << 16);
            e0.w = (er[6] & 0xffffu) | (er[7] << 16);
            e1.x = (er[0] >> 16) | (er[1] & 0xffff0000u);
            e1.y = (er[2] >> 16) | (er[3] & 0xffff0000u);
            e1.z = (er[4] >> 16) | (er[5] & 0xffff0000u);
            e1.w = (er[6] >> 16) | (er[7] & 0xffff0000u);
            int hwg = (sr * 16 + 2 * pl) * 64 + w;
            *(uint4*)(AX + (size_t)hwg * 8) = x0;
            *(uint4*)(AX + (size_t)(hwg + 64) * 8) = x1;
            *(uint4*)(AE + (size_t)hwg * 8) = e0;
            *(uint4*)(AE + (size_t)(hwg + 64) * 8) = e1;
        }
        __syncthreads();
    }
    #pragma unroll
    for (int off = 32; off > 0; off >>= 1) s += __shfl_down(s, off, 64);
    if ((t & 63) == 0) avg[b * 256 + c] = s * (1.0f / HW);
}

// ---------------- SE MLP + fold att into fusion_w[:, :256] (bf16) -----------
__global__ __launch_bounds__(256) void k_sefold(const float* avg, const float* fc1,
                                                const float* fc2, const float* fusw,
                                                ushort_t* w1b)
{
    int b = blockIdx.x, t = threadIdx.x;
    __shared__ float av[256];
    __shared__ float hid[16];
    av[t] = avg[b * 256 + t];
    __syncthreads();
    if (t < 16) {
        float h = 0.f;
        for (int c = 0; c < 256; ++c) h += av[c] * fc1[t * 256 + c];
        hid[t] = h > 0.f ? h : 0.f;
    }
    __syncthreads();
    float a = 0.f;
    #pragma unroll
    for (int j = 0; j < 16; ++j) a += hid[j] * fc2[t * 16 + j];
    float att = 1.0f / (1.0f + expf(-a));
    ushort_t* wout = w1b + (size_t)b * 65536;
    for (int o = 0; o < 256; ++o)
        wout[o * 256 + t] = f2bf(fusw[o * 512 + t] * att);
}

// ---------------- GEMM1: 128hw x 256o (full N, race-free), K=512 ------------
// m97-style: BOTH operands gld16-staged to LDS (coalesced, XOR-swizzled),
// 2 barriers per K-step. 512 thr = 8 waves (2M x 4N). In-place t1 epilogue.
__global__ __launch_bounds__(512, 4) void k_gemm1(ushort_t* __restrict__ A,
                                                  const ushort_t* __restrict__ w1b,
                                                  const ushort_t* __restrict__ fusw2b,
                                                  const float* __restrict__ cbuf)
{
    __shared__ __align__(16) ushort_t At[128 * 64];   // 16 KB
    __shared__ __align__(16) ushort_t Bt[256 * 64];   // 32 KB
    int bid = blockIdx.x;
    int orig = (bid & 7) * 128 + (bid >> 3);          // XCD-chunked remap
    int b = orig >> 5;
    int hw0 = (orig & 31) * 128;
    int t = threadIdx.x;
    int lane = t & 63, wv = t >> 6;
    int quad = lane >> 4, l16 = lane & 15;
    int wr = wv >> 2, wc = wv & 3;                    // 2M x 4N waves
    int srow = lane >> 3, kch = lane & 7;

    v4f acc[4][4];
    #pragma unroll
    for (int i = 0; i < 4; ++i)
        #pragma unroll
        for (int j = 0; j < 4; ++j) acc[i][j] = (v4f){0.f, 0.f, 0.f, 0.f};

    for (int kb = 0; kb < 8; ++kb) {
        __syncthreads();
        // stage A-tile [128m][64k]: 2 rounds, pre-swizzled source chunk
        #pragma unroll
        for (int r = 0; r < 2; ++r) {
            int mrow = wv * 8 + r * 64 + srow;
            int csw = kch ^ (mrow & 7);
            gld16(A + ((size_t)(b * 64 + kb * 8 + csw)) * PLSTRIDE
                    + (size_t)(hw0 + mrow) * 8,
                  &At[(wv * 8 + r * 64) * 64]);
        }
        // stage B-tile [256o][64k]: 4 rounds from w1b / fusw2b rows
        #pragma unroll
        for (int r = 0; r < 4; ++r) {
            int orow = wv * 8 + r * 64 + srow;
            int kc2 = kch ^ (orow & 7);
            const ushort_t* bs = (kb < 4)
                ? (w1b + ((size_t)(b * 256 + orow)) * 256 + kb * 64 + kc2 * 8)
                : (fusw2b + ((size_t)orow) * 256 + (kb - 4) * 64 + kc2 * 8);
            gld16(bs, &Bt[(wv * 8 + r * 64) * 64]);
        }
        __syncthreads();
        #pragma unroll
        for (int ks2 = 0; ks2 < 2; ++ks2) {
            v8s afr[4], bfr[4];
            #pragma unroll
            for (int mt = 0; mt < 4; ++mt) {
                int ml = wr * 64 + mt * 16 + l16;
                int jj = (ks2 * 4 + quad) ^ (ml & 7);
                afr[mt] = *(const v8s*)(&At[ml * 64 + jj * 8]);
            }
            #pragma unroll
            for (int nt = 0; nt < 4; ++nt) {
                int ol = wc * 64 + nt * 16 + l16;
                int jj = (ks2 * 4 + quad) ^ (ol & 7);
                bfr[nt] = *(const v8s*)(&Bt[ol * 64 + jj * 8]);
            }
            #pragma unroll
            for (int mt = 0; mt < 4; ++mt)
                #pragma unroll
                for (int nt = 0; nt < 4; ++nt)
                    acc[mt][nt] = __builtin_amdgcn_mfma_f32_16x16x32_bf16(
                        afr[mt], bfr[nt], acc[mt][nt], 0, 0, 0);
        }
    }

    // epilogue: bn1, write t1 into edge planes of OWN rows (race-free)
    #pragma unroll
    for (int nt = 0; nt < 4; ++nt) {
        int o = wc * 64 + nt * 16 + l16;
        float s1 = cbuf[512 + o], c1 = cbuf[768 + o];
        ushort_t* op = A + ((size_t)(b * 64 + 32 + (o >> 3))) * PLSTRIDE + (o & 7);
        #pragma unroll
        for (int mt = 0; mt < 4; ++mt)
            #pragma unroll
            for (int r = 0; r < 4; ++r) {
                int m = hw0 + wr * 64 + mt * 16 + quad * 4 + r;
                op[(size_t)m * 8] = f2bf(acc[mt][nt][r] * s1 + c1);
            }
    }
}

// ---------------- depthwise 3x3: E-planes -> X-planes, shfl-stencil ---------
// wave = 64 w-columns of one channel-group plane; fully coalesced 16B loads,
// neighbors via __shfl, no LDS, no barriers. grid (8 cgq, 32 b, 2 h-halves).
__global__ __launch_bounds__(256) void k_dw2(ushort_t* __restrict__ A,
                                             const float* __restrict__ dfw)
{
    int t = threadIdx.x;
    int w = t & 63;
    int pl = t >> 6;
    int cg = blockIdx.x * 4 + pl;
    int b = blockIdx.y;
    int h0 = blockIdx.z * 32;
    const ushort_t* pE = A + ((size_t)(b * 64 + 32 + cg)) * PLSTRIDE;
    ushort_t* pX = A + ((size_t)(b * 64 + cg)) * PLSTRIDE;
    float wt[3][3][8];
    #pragma unroll
    for (int r = 0; r < 3; ++r)
        #pragma unroll
        for (int d = 0; d < 3; ++d)
            #pragma unroll
            for (int ch = 0; ch < 8; ++ch)
                wt[r][d][ch] = dfw[(cg * 8 + ch) * 9 + r * 3 + d];
    bool wl = (w > 0), wrr = (w < 63);

    uint4 rm, rc, rp;
    rm = (h0 > 0) ? *(const uint4*)(pE + (size_t)((h0 - 1) * 64 + w) * 8)
                  : (uint4){0u, 0u, 0u, 0u};
    rc = *(const uint4*)(pE + (size_t)(h0 * 64 + w) * 8);

#define DWROW(v, r) { \
    unsigned int cx0 = v.x, cx1 = v.y, cx2 = v.z, cx3 = v.w; \
    unsigned int lx0 = __shfl_up(cx0, 1, 64), lx1 = __shfl_up(cx1, 1, 64); \
    unsigned int lx2 = __shfl_up(cx2, 1, 64), lx3 = __shfl_up(cx3, 1, 64); \
    unsigned int rx0 = __shfl_down(cx0, 1, 64), rx1 = __shfl_down(cx1, 1, 64); \
    unsigned int rx2 = __shfl_down(cx2, 1, 64), rx3 = __shfl_down(cx3, 1, 64); \
    unsigned int cw[4] = { cx0, cx1, cx2, cx3 }; \
    unsigned int lw[4] = { lx0, lx1, lx2, lx3 }; \
    unsigned int rw[4] = { rx0, rx1, rx2, rx3 }; \
    _Pragma("unroll") for (int ch = 0; ch < 8; ++ch) { \
        float fC = bf2f((ch & 1) ? (ushort_t)(cw[ch >> 1] >> 16) \
                                 : (ushort_t)(cw[ch >> 1] & 0xffff)); \
        float fL = wl ? bf2f((ch & 1) ? (ushort_t)(lw[ch >> 1] >> 16) \
                                      : (ushort_t)(lw[ch >> 1] & 0xffff)) : 0.f; \
        float fR = wrr ? bf2f((ch & 1) ? (ushort_t)(rw[ch >> 1] >> 16) \
                                       : (ushort_t)(rw[ch >> 1] & 0xffff)) : 0.f; \
        acc[ch] += fL * wt[r][0][ch] + fC * wt[r][1][ch] + fR * wt[r][2][ch]; \
    } }

    for (int s = 0; s < 32; ++s) {
        int h = h0 + s;
        rp = (h + 1 < 64) ? *(const uint4*)(pE + (size_t)((h + 1) * 64 + w) * 8)
                          : (uint4){0u, 0u, 0u, 0u};
        float acc[8];
        #pragma unroll
        for (int ch = 0; ch < 8; ++ch) acc[ch] = 0.f;
        DWROW(rm, 0);
        DWROW(rc, 1);
        DWROW(rp, 2);
        uint4 ov;
        ov.x = (unsigned int)f2bf(acc[0]) | ((unsigned int)f2bf(acc[1]) << 16);
        ov.y = (unsigned int)f2bf(acc[2]) | ((unsigned int)f2bf(acc[3]) << 16);
        ov.z = (unsigned int)f2bf(acc[4]) | ((unsigned int)f2bf(acc[5]) << 16);
        ov.w = (unsigned int)f2bf(acc[6]) | ((unsigned int)f2bf(acc[7]) << 16);
        *(uint4*)(pX + (size_t)(h * 64 + w) * 8) = ov;
        rm = rc; rc = rp;
    }
#undef DWROW
}

// ---------------- GEMM2: 128hw x 256o (full N), K=256, m97-style ------------
__global__ __launch_bounds__(512, 4) void k_gemm2(ushort_t* __restrict__ A,
                                                  const ushort_t* __restrict__ balwb)
{
    __shared__ __align__(16) ushort_t At[128 * 64];   // 16 KB
    __shared__ __align__(16) ushort_t Bt[256 * 64];   // 32 KB
    int bid = blockIdx.x;
    int orig = (bid & 7) * 128 + (bid >> 3);
    int b = orig >> 5;
    int hw0 = (orig & 31) * 128;
    int t = threadIdx.x;
    int lane = t & 63, wv = t >> 6;
    int quad = lane >> 4, l16 = lane & 15;
    int wr = wv >> 2, wc = wv & 3;
    int srow = lane >> 3, kch = lane & 7;

    v4f acc[4][4];
    #pragma unroll
    for (int i = 0; i < 4; ++i)
        #pragma unroll
        for (int j = 0; j < 4; ++j) acc[i][j] = (v4f){0.f, 0.f, 0.f, 0.f};

    for (int kb = 0; kb < 4; ++kb) {
        __syncthreads();
        #pragma unroll
        for (int r = 0; r < 2; ++r) {
            int mrow = wv * 8 + r * 64 + srow;
            int csw = kch ^ (mrow & 7);
            gld16(A + ((size_t)(b * 64 + kb * 8 + csw)) * PLSTRIDE
                    + (size_t)(hw0 + mrow) * 8,
                  &At[(wv * 8 + r * 64) * 64]);
        }
        #pragma unroll
        for (int r = 0; r < 4; ++r) {
            int orow = wv * 8 + r * 64 + srow;
            int kc2 = kch ^ (orow & 7);
            gld16(balwb + ((size_t)orow) * 256 + kb * 64 + kc2 * 8,
                  &Bt[(wv * 8 + r * 64) * 64]);
        }
        __syncthreads();
        #pragma unroll
        for (int ks2 = 0; ks2 < 2; ++ks2) {
            v8s afr[4], bfr[4];
            #pragma unroll
            for (int mt = 0; mt < 4; ++mt) {
                int ml = wr * 64 + mt * 16 + l16;
                int jj = (ks2 * 4 + quad) ^ (ml & 7);
                afr[mt] = *(const v8s*)(&At[ml * 64 + jj * 8]);
            }
            #pragma unroll
            for (int nt = 0; nt < 4; ++nt) {
                int ol = wc * 64 + nt * 16 + l16;
                int jj = (ks2 * 4 + quad) ^ (ol & 7);
                bfr[nt] = *(const v8s*)(&Bt[ol * 64 + jj * 8]);
            }
            #pragma unroll
            for (int mt = 0; mt < 4; ++mt)
                #pragma unroll
                for (int nt = 0; nt < 4; ++nt)
                    acc[mt][nt] = __builtin_amdgcn_mfma_f32_16x16x32_bf16(
                        afr[mt], bfr[nt], acc[mt][nt], 0, 0, 0);
        }
    }

    #pragma unroll
    for (int nt = 0; nt < 4; ++nt) {
        int o = wc * 64 + nt * 16 + l16;
        ushort_t* op = A + ((size_t)(b * 64 + 32 + (o >> 3))) * PLSTRIDE + (o & 7);
        #pragma unroll
        for (int mt = 0; mt < 4; ++mt)
            #pragma unroll
            for (int r = 0; r < 4; ++r) {
                int m = hw0 + wr * 64 + mt * 16 + quad * 4 + r;
                op[(size_t)m * 8] = f2bf(acc[mt][nt][r]);
            }
    }
}

// ---------------- final: blocked->NCHW transpose + BN2 + gate by x ----------
__global__ __launch_bounds__(256) void k_final(const ushort_t* A, const float* x,
                                               const float* cbuf, float* out)
{
    __shared__ float Lt[64 * 65];
    int bid = blockIdx.x;
    int b = bid >> 8;
    int rem = bid & 255;
    int hw0 = (rem >> 2) * 64;
    int c0 = (rem & 3) * 64;
    int t = threadIdx.x;
    #pragma unroll
    for (int r = 0; r < 2; ++r) {
        int idx = r * 256 + t;
        int cq = idx >> 6;          // plane within the 64-ch group
        int hwl = idx & 63;         // lanes sweep hw -> coalesced 1KB reads
        uint4 v = *(const uint4*)(A + ((size_t)(b * 64 + 32 + (c0 >> 3) + cq)) * PLSTRIDE
                                    + (size_t)(hw0 + hwl) * 8);
        unsigned int wd[4] = { v.x, v.y, v.z, v.w };
        #pragma unroll
        for (int j = 0; j < 8; ++j) {
            ushort_t u = (j & 1) ? (ushort_t)(wd[j >> 1] >> 16) : (ushort_t)(wd[j >> 1] & 0xffff);
            Lt[(cq * 8 + j) * 65 + hwl] = bf2f(u);
        }
    }
    __syncthreads();
    int hw_l = t & 63;
    int c_l0 = t >> 6;
    #pragma unroll
    for (int j = 0; j < 16; ++j) {
        int c_l = c_l0 * 16 + j;
        int c = c0 + c_l;
        float s2 = cbuf[1024 + c], c2 = cbuf[1280 + c];
        size_t g = ((size_t)b * 256 + c) * HW + hw0 + hw_l;
        float xv = x[g];
        out[g] = (Lt[c_l * 65 + hw_l] * s2 + c2) * xv;
    }
}

extern "C" void kernel_launch(void* const* d_in, const int* in_sizes, int n_in,
                              void* d_out, int out_size, void* d_ws, size_t ws_size,
                              hipStream_t stream)
{
    const float* x    = (const float*)d_in[0];
    const float* ew   = (const float*)d_in[1];
    const float* fc1  = (const float*)d_in[6];
    const float* fc2  = (const float*)d_in[7];
    const float* fusw = (const float*)d_in[8];
    const float* dfw  = (const float*)d_in[14];
    const float* balw = (const float*)d_in[15];
    float* out = (float*)d_out;

    char* ws = (char*)d_ws;
    ushort_t* A      = (ushort_t*)(ws);                 // 134217728 B
    ushort_t* w1b    = (ushort_t*)(ws + 134217728);     // 4 MiB
    ushort_t* fusw2b = (ushort_t*)(ws + 138412032);     // 128 KiB
    ushort_t* balwb  = (ushort_t*)(ws + 138543104);     // 128 KiB
    float*    avg    = (float*)(ws + 138674176);        // 32 KiB
    float*    cbuf   = (float*)(ws + 138706944);        // 6 KiB

    k_consts<<<1, 256, 0, stream>>>((const float*)d_in[2], (const float*)d_in[3],
                                    (const float*)d_in[4], (const float*)d_in[5],
                                    (const float*)d_in[9],
                                    (const float*)d_in[10], (const float*)d_in[11],
                                    (const float*)d_in[12], (const float*)d_in[13],
                                    (const float*)d_in[16],
                                    (const float*)d_in[17], (const float*)d_in[18],
                                    (const float*)d_in[19], (const float*)d_in[20],
                                    cbuf);
    k_wcopy<<<256, 256, 0, stream>>>(fusw, balw, fusw2b, balwb);
    k_edge<<<dim3(32, 32), 512, 0, stream>>>(x, ew, cbuf, A, avg);
    k_sefold<<<32, 256, 0, stream>>>(avg, fc1, fc2, fusw, w1b);
    k_gemm1<<<1024, 512, 0, stream>>>(A, w1b, fusw2b, cbuf);
    k_dw2<<<dim3(8, 32, 2), 256, 0, stream>>>(A, dfw);
    k_gemm2<<<1024, 512, 0, stream>>>(A, balwb);
    k_final<<<8192, 256, 0, stream>>>(A, x, cbuf, out);
}

// Round 6
// 527.683 us; speedup vs baseline: 1.2290x; 1.0135x over previous
//
#include <hip/hip_runtime.h>
#include <math.h>

#define HW 4096
#define PLSTRIDE ((size_t)HW * 8)   // elements per 8-channel plane of A

typedef unsigned short ushort_t;
typedef short v8s __attribute__((ext_vector_type(8)));
typedef float v4f __attribute__((ext_vector_type(4)));

__device__ __forceinline__ float bf2f(ushort_t u) {
    union { unsigned int i; float f; } v; v.i = ((unsigned int)u) << 16; return v.f;
}
__device__ __forceinline__ ushort_t f2bf(float f) {
    unsigned int x = __float_as_uint(f);
    x += 0x7fffu + ((x >> 16) & 1u);   // RNE
    return (ushort_t)(x >> 16);
}

// async global->LDS, 16B per lane; LDS dest = wave-uniform base + lane*16
__device__ __forceinline__ void gld16(const ushort_t* g, ushort_t* l) {
    __builtin_amdgcn_global_load_lds(
        (__attribute__((address_space(1))) void*)g,
        (__attribute__((address_space(3))) void*)l, 16, 0, 0);
}

// ---------------- per-channel constants -------------------------------------
// cbuf layout (floats): [0]=sE [256]=cE [512]=s1 [768]=c1 [1024]=s2 [1280]=c2
__global__ __launch_bounds__(256) void k_consts(
    const float* eg, const float* ebt, const float* em, const float* ev,
    const float* fb,
    const float* g1, const float* b1, const float* m1, const float* v1,
    const float* balb,
    const float* g2, const float* b2, const float* m2, const float* v2,
    float* cbuf)
{
    int c = threadIdx.x;
    float iE = eg[c] * rsqrtf(ev[c] + 1e-5f);
    cbuf[c]       = iE;
    cbuf[256 + c] = ebt[c] - em[c] * iE;
    float i1 = g1[c] * rsqrtf(v1[c] + 1e-5f);
    cbuf[512 + c] = i1;
    cbuf[768 + c] = b1[c] - m1[c] * i1 + fb[c] * i1;
    float i2 = g2[c] * rsqrtf(v2[c] + 1e-5f);
    cbuf[1024 + c] = i2;
    cbuf[1280 + c] = b2[c] - m2[c] * i2 + balb[c] * i2;
}

// ---------------- bf16 copies of shared weights -----------------------------
__global__ __launch_bounds__(256) void k_wcopy(const float* fusw, const float* balw,
                                               ushort_t* fusw2b, ushort_t* balwb)
{
    int o = blockIdx.x, t = threadIdx.x;
    fusw2b[o * 256 + t] = f2bf(fusw[o * 512 + 256 + t]);
    balwb[o * 256 + t]  = f2bf(balw[o * 256 + t]);
}

// ---------------- edge dw3x3+BN+relu, bf16(x) copy, SE avg ------------------
// 4-wide vectorized stencil: lane (q = row-in-group, l16 = w-chunk) loads
// 3 x float4 and computes 4 outputs -> VMEM instrs 192->48 (16B each),
// serial h-chain 64->16 steps. Horizontal halo via shfl. Conflict-free
// u32 LDS transpose [r16][ch][wp ^ (r16&7)] (2 lanes/bank both sides).
__global__ __launch_bounds__(512) void k_edge(const float* x, const float* ew,
                                              const float* cbuf, ushort_t* A,
                                              float* avg)
{
    __shared__ unsigned int Xs[16][8][32];   // 16 KB
    __shared__ unsigned int Es[16][8][32];   // 16 KB
    int cg = blockIdx.x;
    int b = blockIdx.y;
    int t = threadIdx.x;
    int lane = t & 63;
    int pl = t >> 6;                    // wave index = channel within group
    int q = lane >> 4;                  // row-in-group 0..3
    int l16 = lane & 15;                // w-chunk
    int w4 = l16 * 4;
    int c = cg * 8 + pl;
    const float* px = x + ((size_t)(b * 256 + c)) * HW;
    ushort_t* AX = A + ((size_t)(b * 64 + cg)) * PLSTRIDE;
    ushort_t* AE = A + ((size_t)(b * 64 + 32 + cg)) * PLSTRIDE;
    float wt[9];
    #pragma unroll
    for (int k = 0; k < 9; ++k) wt[k] = ew[c * 9 + k];
    float sE = cbuf[c], cE = cbuf[256 + c];
    bool wlz = (l16 > 0), wrz = (l16 < 15);
    float s = 0.f;

    for (int g4 = 0; g4 < 4; ++g4) {
        #pragma unroll
        for (int gi = 0; gi < 4; ++gi) {
            int h = (g4 * 4 + gi) * 4 + q;
            const float* rowp = px + h * 64 + w4;
            float4 vc = *(const float4*)rowp;
            float4 vm = (h > 0)  ? *(const float4*)(rowp - 64)
                                 : make_float4(0.f, 0.f, 0.f, 0.f);
            float4 vp = (h < 63) ? *(const float4*)(rowp + 64)
                                 : make_float4(0.f, 0.f, 0.f, 0.f);
            // horizontal halo (within-row; q-boundary lanes masked by w-edge)
            float lm_ = __shfl_up(vm.w, 1, 64);  float lm = wlz ? lm_ : 0.f;
            float lc_ = __shfl_up(vc.w, 1, 64);  float lc = wlz ? lc_ : 0.f;
            float lp_ = __shfl_up(vp.w, 1, 64);  float lp = wlz ? lp_ : 0.f;
            float rm_ = __shfl_down(vm.x, 1, 64); float rm = wrz ? rm_ : 0.f;
            float rc_ = __shfl_down(vc.x, 1, 64); float rc = wrz ? rc_ : 0.f;
            float rp_ = __shfl_down(vp.x, 1, 64); float rp = wrz ? rp_ : 0.f;

            float o0 = lm   * wt[0] + vm.x * wt[1] + vm.y * wt[2]
                     + lc   * wt[3] + vc.x * wt[4] + vc.y * wt[5]
                     + lp   * wt[6] + vp.x * wt[7] + vp.y * wt[8];
            float o1 = vm.x * wt[0] + vm.y * wt[1] + vm.z * wt[2]
                     + vc.x * wt[3] + vc.y * wt[4] + vc.z * wt[5]
                     + vp.x * wt[6] + vp.y * wt[7] + vp.z * wt[8];
            float o2 = vm.y * wt[0] + vm.z * wt[1] + vm.w * wt[2]
                     + vc.y * wt[3] + vc.z * wt[4] + vc.w * wt[5]
                     + vp.y * wt[6] + vp.z * wt[7] + vp.w * wt[8];
            float o3 = vm.z * wt[0] + vm.w * wt[1] + rm   * wt[2]
                     + vc.z * wt[3] + vc.w * wt[4] + rc   * wt[5]
                     + vp.z * wt[6] + vp.w * wt[7] + rp   * wt[8];

            float e0 = o0 * sE + cE; e0 = e0 > 0.f ? e0 : 0.f;
            float e1 = o1 * sE + cE; e1 = e1 > 0.f ? e1 : 0.f;
            float e2 = o2 * sE + cE; e2 = e2 > 0.f ? e2 : 0.f;
            float e3 = o3 * sE + cE; e3 = e3 > 0.f ? e3 : 0.f;

            unsigned int xlo = (unsigned int)f2bf(vc.x) | ((unsigned int)f2bf(vc.y) << 16);
            unsigned int xhi = (unsigned int)f2bf(vc.z) | ((unsigned int)f2bf(vc.w) << 16);
            unsigned int elo = (unsigned int)f2bf(e0) | ((unsigned int)f2bf(e1) << 16);
            unsigned int ehi = (unsigned int)f2bf(e2) | ((unsigned int)f2bf(e3) << 16);

            int r16 = gi * 4 + q;
            int sz = r16 & 7;
            Xs[r16][pl][(2 * l16) ^ sz]     = xlo;
            Xs[r16][pl][(2 * l16 + 1) ^ sz] = xhi;
            Es[r16][pl][(2 * l16) ^ sz]     = elo;
            Es[r16][pl][(2 * l16 + 1) ^ sz] = ehi;
            s += vc.x + vc.y + vc.z + vc.w;
        }
        __syncthreads();
        {
            // flush 16 rows: thread (r16 = t>>5, w2 = t&31) -> w = 2*w2, 2*w2+1
            int r16 = t >> 5;
            int w2 = t & 31;
            int sz = r16 & 7;
            unsigned int ux[8], ue[8];
            #pragma unroll
            for (int ch = 0; ch < 8; ++ch) {
                ux[ch] = Xs[r16][ch][w2 ^ sz];
                ue[ch] = Es[r16][ch][w2 ^ sz];
            }
            uint4 x0, x1, e0v, e1v;
            x0.x = (ux[0] & 0xffffu) | (ux[1] << 16);
            x0.y = (ux[2] & 0xffffu) | (ux[3] << 16);
            x0.z = (ux[4] & 0xffffu) | (ux[5] << 16);
            x0.w = (ux[6] & 0xffffu) | (ux[7] << 16);
            x1.x = (ux[0] >> 16) | (ux[1] & 0xffff0000u);
            x1.y = (ux[2] >> 16) | (ux[3] & 0xffff0000u);
            x1.z = (ux[4] >> 16) | (ux[5] & 0xffff0000u);
            x1.w = (ux[6] >> 16) | (ux[7] & 0xffff0000u);
            e0v.x = (ue[0] & 0xffffu) | (ue[1] << 16);
            e0v.y = (ue[2] & 0xffffu) | (ue[3] << 16);
            e0v.z = (ue[4] & 0xffffu) | (ue[5] << 16);
            e0v.w = (ue[6] & 0xffffu) | (ue[7] << 16);
            e1v.x = (ue[0] >> 16) | (ue[1] & 0xffff0000u);
            e1v.y = (ue[2] >> 16) | (ue[3] & 0xffff0000u);
            e1v.z = (ue[4] >> 16) | (ue[5] & 0xffff0000u);
            e1v.w = (ue[6] >> 16) | (ue[7] & 0xffff0000u);
            int hwg = (g4 * 16 + r16) * 64 + 2 * w2;
            *(uint4*)(AX + (size_t)hwg * 8) = x0;
            *(uint4*)(AX + (size_t)(hwg + 1) * 8) = x1;
            *(uint4*)(AE + (size_t)hwg * 8) = e0v;
            *(uint4*)(AE + (size_t)(hwg + 1) * 8) = e1v;
        }
        __syncthreads();
    }
    #pragma unroll
    for (int off = 32; off > 0; off >>= 1) s += __shfl_down(s, off, 64);
    if ((t & 63) == 0) avg[b * 256 + c] = s * (1.0f / HW);
}

// ---------------- SE MLP + fold att into fusion_w[:, :256] (bf16) -----------
__global__ __launch_bounds__(256) void k_sefold(const float* avg, const float* fc1,
                                                const float* fc2, const float* fusw,
                                                ushort_t* w1b)
{
    int b = blockIdx.x, t = threadIdx.x;
    __shared__ float av[256];
    __shared__ float hid[16];
    av[t] = avg[b * 256 + t];
    __syncthreads();
    if (t < 16) {
        float h = 0.f;
        for (int c = 0; c < 256; ++c) h += av[c] * fc1[t * 256 + c];
        hid[t] = h > 0.f ? h : 0.f;
    }
    __syncthreads();
    float a = 0.f;
    #pragma unroll
    for (int j = 0; j < 16; ++j) a += hid[j] * fc2[t * 16 + j];
    float att = 1.0f / (1.0f + expf(-a));
    ushort_t* wout = w1b + (size_t)b * 65536;
    for (int o = 0; o < 256; ++o)
        wout[o * 256 + t] = f2bf(fusw[o * 512 + t] * att);
}

// ---------------- GEMM1: 128hw x 256o (full N, race-free), K=512 ------------
// m97-style: BOTH operands gld16-staged to LDS (coalesced, XOR-swizzled),
// 2 barriers per K-step. 512 thr = 8 waves (2M x 4N). In-place t1 epilogue.
__global__ __launch_bounds__(512, 4) void k_gemm1(ushort_t* __restrict__ A,
                                                  const ushort_t* __restrict__ w1b,
                                                  const ushort_t* __restrict__ fusw2b,
                                                  const float* __restrict__ cbuf)
{
    __shared__ __align__(16) ushort_t At[128 * 64];   // 16 KB
    __shared__ __align__(16) ushort_t Bt[256 * 64];   // 32 KB
    int bid = blockIdx.x;
    int orig = (bid & 7) * 128 + (bid >> 3);          // XCD-chunked remap
    int b = orig >> 5;
    int hw0 = (orig & 31) * 128;
    int t = threadIdx.x;
    int lane = t & 63, wv = t >> 6;
    int quad = lane >> 4, l16 = lane & 15;
    int wr = wv >> 2, wc = wv & 3;                    // 2M x 4N waves
    int srow = lane >> 3, kch = lane & 7;

    v4f acc[4][4];
    #pragma unroll
    for (int i = 0; i < 4; ++i)
        #pragma unroll
        for (int j = 0; j < 4; ++j) acc[i][j] = (v4f){0.f, 0.f, 0.f, 0.f};

    for (int kb = 0; kb < 8; ++kb) {
        __syncthreads();
        // stage A-tile [128m][64k]: 2 rounds, pre-swizzled source chunk
        #pragma unroll
        for (int r = 0; r < 2; ++r) {
            int mrow = wv * 8 + r * 64 + srow;
            int csw = kch ^ (mrow & 7);
            gld16(A + ((size_t)(b * 64 + kb * 8 + csw)) * PLSTRIDE
                    + (size_t)(hw0 + mrow) * 8,
                  &At[(wv * 8 + r * 64) * 64]);
        }
        // stage B-tile [256o][64k]: 4 rounds from w1b / fusw2b rows
        #pragma unroll
        for (int r = 0; r < 4; ++r) {
            int orow = wv * 8 + r * 64 + srow;
            int kc2 = kch ^ (orow & 7);
            const ushort_t* bs = (kb < 4)
                ? (w1b + ((size_t)(b * 256 + orow)) * 256 + kb * 64 + kc2 * 8)
                : (fusw2b + ((size_t)orow) * 256 + (kb - 4) * 64 + kc2 * 8);
            gld16(bs, &Bt[(wv * 8 + r * 64) * 64]);
        }
        __syncthreads();
        #pragma unroll
        for (int ks2 = 0; ks2 < 2; ++ks2) {
            v8s afr[4], bfr[4];
            #pragma unroll
            for (int mt = 0; mt < 4; ++mt) {
                int ml = wr * 64 + mt * 16 + l16;
                int jj = (ks2 * 4 + quad) ^ (ml & 7);
                afr[mt] = *(const v8s*)(&At[ml * 64 + jj * 8]);
            }
            #pragma unroll
            for (int nt = 0; nt < 4; ++nt) {
                int ol = wc * 64 + nt * 16 + l16;
                int jj = (ks2 * 4 + quad) ^ (ol & 7);
                bfr[nt] = *(const v8s*)(&Bt[ol * 64 + jj * 8]);
            }
            #pragma unroll
            for (int mt = 0; mt < 4; ++mt)
                #pragma unroll
                for (int nt = 0; nt < 4; ++nt)
                    acc[mt][nt] = __builtin_amdgcn_mfma_f32_16x16x32_bf16(
                        afr[mt], bfr[nt], acc[mt][nt], 0, 0, 0);
        }
    }

    // epilogue: bn1, write t1 into edge planes of OWN rows (race-free)
    #pragma unroll
    for (int nt = 0; nt < 4; ++nt) {
        int o = wc * 64 + nt * 16 + l16;
        float s1 = cbuf[512 + o], c1 = cbuf[768 + o];
        ushort_t* op = A + ((size_t)(b * 64 + 32 + (o >> 3))) * PLSTRIDE + (o & 7);
        #pragma unroll
        for (int mt = 0; mt < 4; ++mt)
            #pragma unroll
            for (int r = 0; r < 4; ++r) {
                int m = hw0 + wr * 64 + mt * 16 + quad * 4 + r;
                op[(size_t)m * 8] = f2bf(acc[mt][nt][r] * s1 + c1);
            }
    }
}

// ---------------- depthwise 3x3: E-planes -> X-planes, shfl-stencil ---------
// wave = 64 w-columns of one channel-group plane; fully coalesced 16B loads,
// neighbors via __shfl, no LDS, no barriers. grid (8 cgq, 32 b, 2 h-halves).
__global__ __launch_bounds__(256) void k_dw2(ushort_t* __restrict__ A,
                                             const float* __restrict__ dfw)
{
    int t = threadIdx.x;
    int w = t & 63;
    int pl = t >> 6;
    int cg = blockIdx.x * 4 + pl;
    int b = blockIdx.y;
    int h0 = blockIdx.z * 32;
    const ushort_t* pE = A + ((size_t)(b * 64 + 32 + cg)) * PLSTRIDE;
    ushort_t* pX = A + ((size_t)(b * 64 + cg)) * PLSTRIDE;
    float wt[3][3][8];
    #pragma unroll
    for (int r = 0; r < 3; ++r)
        #pragma unroll
        for (int d = 0; d < 3; ++d)
            #pragma unroll
            for (int ch = 0; ch < 8; ++ch)
                wt[r][d][ch] = dfw[(cg * 8 + ch) * 9 + r * 3 + d];
    bool wl = (w > 0), wrr = (w < 63);

    uint4 rm, rc, rp;
    rm = (h0 > 0) ? *(const uint4*)(pE + (size_t)((h0 - 1) * 64 + w) * 8)
                  : (uint4){0u, 0u, 0u, 0u};
    rc = *(const uint4*)(pE + (size_t)(h0 * 64 + w) * 8);

#define DWROW(v, r) { \
    unsigned int cx0 = v.x, cx1 = v.y, cx2 = v.z, cx3 = v.w; \
    unsigned int lx0 = __shfl_up(cx0, 1, 64), lx1 = __shfl_up(cx1, 1, 64); \
    unsigned int lx2 = __shfl_up(cx2, 1, 64), lx3 = __shfl_up(cx3, 1, 64); \
    unsigned int rx0 = __shfl_down(cx0, 1, 64), rx1 = __shfl_down(cx1, 1, 64); \
    unsigned int rx2 = __shfl_down(cx2, 1, 64), rx3 = __shfl_down(cx3, 1, 64); \
    unsigned int cw[4] = { cx0, cx1, cx2, cx3 }; \
    unsigned int lw[4] = { lx0, lx1, lx2, lx3 }; \
    unsigned int rw[4] = { rx0, rx1, rx2, rx3 }; \
    _Pragma("unroll") for (int ch = 0; ch < 8; ++ch) { \
        float fC = bf2f((ch & 1) ? (ushort_t)(cw[ch >> 1] >> 16) \
                                 : (ushort_t)(cw[ch >> 1] & 0xffff)); \
        float fL = wl ? bf2f((ch & 1) ? (ushort_t)(lw[ch >> 1] >> 16) \
                                      : (ushort_t)(lw[ch >> 1] & 0xffff)) : 0.f; \
        float fR = wrr ? bf2f((ch & 1) ? (ushort_t)(rw[ch >> 1] >> 16) \
                                       : (ushort_t)(rw[ch >> 1] & 0xffff)) : 0.f; \
        acc[ch] += fL * wt[r][0][ch] + fC * wt[r][1][ch] + fR * wt[r][2][ch]; \
    } }

    for (int s = 0; s < 32; ++s) {
        int h = h0 + s;
        rp = (h + 1 < 64) ? *(const uint4*)(pE + (size_t)((h + 1) * 64 + w) * 8)
                          : (uint4){0u, 0u, 0u, 0u};
        float acc[8];
        #pragma unroll
        for (int ch = 0; ch < 8; ++ch) acc[ch] = 0.f;
        DWROW(rm, 0);
        DWROW(rc, 1);
        DWROW(rp, 2);
        uint4 ov;
        ov.x = (unsigned int)f2bf(acc[0]) | ((unsigned int)f2bf(acc[1]) << 16);
        ov.y = (unsigned int)f2bf(acc[2]) | ((unsigned int)f2bf(acc[3]) << 16);
        ov.z = (unsigned int)f2bf(acc[4]) | ((unsigned int)f2bf(acc[5]) << 16);
        ov.w = (unsigned int)f2bf(acc[6]) | ((unsigned int)f2bf(acc[7]) << 16);
        *(uint4*)(pX + (size_t)(h * 64 + w) * 8) = ov;
        rm = rc; rc = rp;
    }
#undef DWROW
}

// ---------------- GEMM2: 128hw x 256o (full N), K=256, m97-style ------------
__global__ __launch_bounds__(512, 4) void k_gemm2(ushort_t* __restrict__ A,
                                                  const ushort_t* __restrict__ balwb)
{
    __shared__ __align__(16) ushort_t At[128 * 64];   // 16 KB
    __shared__ __align__(16) ushort_t Bt[256 * 64];   // 32 KB
    int bid = blockIdx.x;
    int orig = (bid & 7) * 128 + (bid >> 3);
    int b = orig >> 5;
    int hw0 = (orig & 31) * 128;
    int t = threadIdx.x;
    int lane = t & 63, wv = t >> 6;
    int quad = lane >> 4, l16 = lane & 15;
    int wr = wv >> 2, wc = wv & 3;
    int srow = lane >> 3, kch = lane & 7;

    v4f acc[4][4];
    #pragma unroll
    for (int i = 0; i < 4; ++i)
        #pragma unroll
        for (int j = 0; j < 4; ++j) acc[i][j] = (v4f){0.f, 0.f, 0.f, 0.f};

    for (int kb = 0; kb < 4; ++kb) {
        __syncthreads();
        #pragma unroll
        for (int r = 0; r < 2; ++r) {
            int mrow = wv * 8 + r * 64 + srow;
            int csw = kch ^ (mrow & 7);
            gld16(A + ((size_t)(b * 64 + kb * 8 + csw)) * PLSTRIDE
                    + (size_t)(hw0 + mrow) * 8,
                  &At[(wv * 8 + r * 64) * 64]);
        }
        #pragma unroll
        for (int r = 0; r < 4; ++r) {
            int orow = wv * 8 + r * 64 + srow;
            int kc2 = kch ^ (orow & 7);
            gld16(balwb + ((size_t)orow) * 256 + kb * 64 + kc2 * 8,
                  &Bt[(wv * 8 + r * 64) * 64]);
        }
        __syncthreads();
        #pragma unroll
        for (int ks2 = 0; ks2 < 2; ++ks2) {
            v8s afr[4], bfr[4];
            #pragma unroll
            for (int mt = 0; mt < 4; ++mt) {
                int ml = wr * 64 + mt * 16 + l16;
                int jj = (ks2 * 4 + quad) ^ (ml & 7);
                afr[mt] = *(const v8s*)(&At[ml * 64 + jj * 8]);
            }
            #pragma unroll
            for (int nt = 0; nt < 4; ++nt) {
                int ol = wc * 64 + nt * 16 + l16;
                int jj = (ks2 * 4 + quad) ^ (ol & 7);
                bfr[nt] = *(const v8s*)(&Bt[ol * 64 + jj * 8]);
            }
            #pragma unroll
            for (int mt = 0; mt < 4; ++mt)
                #pragma unroll
                for (int nt = 0; nt < 4; ++nt)
                    acc[mt][nt] = __builtin_amdgcn_mfma_f32_16x16x32_bf16(
                        afr[mt], bfr[nt], acc[mt][nt], 0, 0, 0);
        }
    }

    #pragma unroll
    for (int nt = 0; nt < 4; ++nt) {
        int o = wc * 64 + nt * 16 + l16;
        ushort_t* op = A + ((size_t)(b * 64 + 32 + (o >> 3))) * PLSTRIDE + (o & 7);
        #pragma unroll
        for (int mt = 0; mt < 4; ++mt)
            #pragma unroll
            for (int r = 0; r < 4; ++r) {
                int m = hw0 + wr * 64 + mt * 16 + quad * 4 + r;
                op[(size_t)m * 8] = f2bf(acc[mt][nt][r]);
            }
    }
}

// ---------------- final: blocked->NCHW transpose + BN2 + gate by x ----------
__global__ __launch_bounds__(256) void k_final(const ushort_t* A, const float* x,
                                               const float* cbuf, float* out)
{
    __shared__ float Lt[64 * 65];
    int bid = blockIdx.x;
    int b = bid >> 8;
    int rem = bid & 255;
    int hw0 = (rem >> 2) * 64;
    int c0 = (rem & 3) * 64;
    int t = threadIdx.x;
    #pragma unroll
    for (int r = 0; r < 2; ++r) {
        int idx = r * 256 + t;
        int cq = idx >> 6;          // plane within the 64-ch group
        int hwl = idx & 63;         // lanes sweep hw -> coalesced 1KB reads
        uint4 v = *(const uint4*)(A + ((size_t)(b * 64 + 32 + (c0 >> 3) + cq)) * PLSTRIDE
                                    + (size_t)(hw0 + hwl) * 8);
        unsigned int wd[4] = { v.x, v.y, v.z, v.w };
        #pragma unroll
        for (int j = 0; j < 8; ++j) {
            ushort_t u = (j & 1) ? (ushort_t)(wd[j >> 1] >> 16) : (ushort_t)(wd[j >> 1] & 0xffff);
            Lt[(cq * 8 + j) * 65 + hwl] = bf2f(u);
        }
    }
    __syncthreads();
    int hw_l = t & 63;
    int c_l0 = t >> 6;
    #pragma unroll
    for (int j = 0; j < 16; ++j) {
        int c_l = c_l0 * 16 + j;
        int c = c0 + c_l;
        float s2 = cbuf[1024 + c], c2 = cbuf[1280 + c];
        size_t g = ((size_t)b * 256 + c) * HW + hw0 + hw_l;
        float xv = x[g];
        out[g] = (Lt[c_l * 65 + hw_l] * s2 + c2) * xv;
    }
}

extern "C" void kernel_launch(void* const* d_in, const int* in_sizes, int n_in,
                              void* d_out, int out_size, void* d_ws, size_t ws_size,
                              hipStream_t stream)
{
    const float* x    = (const float*)d_in[0];
    const float* ew   = (const float*)d_in[1];
    const float* fc1  = (const float*)d_in[6];
    const float* fc2  = (const float*)d_in[7];
    const float* fusw = (const float*)d_in[8];
    const float* dfw  = (const float*)d_in[14];
    const float* balw = (const float*)d_in[15];
    float* out = (float*)d_out;

    char* ws = (char*)d_ws;
    ushort_t* A      = (ushort_t*)(ws);                 // 134217728 B
    ushort_t* w1b    = (ushort_t*)(ws + 134217728);     // 4 MiB
    ushort_t* fusw2b = (ushort_t*)(ws + 138412032);     // 128 KiB
    ushort_t* balwb  = (ushort_t*)(ws + 138543104);     // 128 KiB
    float*    avg    = (float*)(ws + 138674176);        // 32 KiB
    float*    cbuf   = (float*)(ws + 138706944);        // 6 KiB

    k_consts<<<1, 256, 0, stream>>>((const float*)d_in[2], (const float*)d_in[3],
                                    (const float*)d_in[4], (const float*)d_in[5],
                                    (const float*)d_in[9],
                                    (const float*)d_in[10], (const float*)d_in[11],
                                    (const float*)d_in[12], (const float*)d_in[13],
                                    (const float*)d_in[16],
                                    (const float*)d_in[17], (const float*)d_in[18],
                                    (const float*)d_in[19], (const float*)d_in[20],
                                    cbuf);
    k_wcopy<<<256, 256, 0, stream>>>(fusw, balw, fusw2b, balwb);
    k_edge<<<dim3(32, 32), 512, 0, stream>>>(x, ew, cbuf, A, avg);
    k_sefold<<<32, 256, 0, stream>>>(avg, fc1, fc2, fusw, w1b);
    k_gemm1<<<1024, 512, 0, stream>>>(A, w1b, fusw2b, cbuf);
    k_dw2<<<dim3(8, 32, 2), 256, 0, stream>>>(A, dfw);
    k_gemm2<<<1024, 512, 0, stream>>>(A, balwb);
    k_final<<<8192, 256, 0, stream>>>(A, x, cbuf, out);
}